// Round 6
// baseline (13206.868 us; speedup 1.0000x reference)
//
#include <hip/hip_runtime.h>
#include <hip/hip_cooperative_groups.h>
#include <math.h>

namespace cg = cooperative_groups;

#define B 32
#define T 128
#define H 512
#define E 512
#define ODIM 256
#define STEPS 16
#define G3 1536
#define BH (B * H)
#define NBLK 256
#define NTHR 512

typedef float4 f4;

__device__ __forceinline__ float sigmoidf_(float x) { return 1.0f / (1.0f + __expf(-x)); }
__device__ __forceinline__ float tanh_fast(float x) {
    float t = __expf(-2.0f * fabsf(x));
    float r = (1.0f - t) / (1.0f + t);
    return __builtin_copysignf(r, x);
}
__device__ __forceinline__ void fma4(f4& a, float s, const f4 w) {
    a.x = fmaf(s, w.x, a.x); a.y = fmaf(s, w.y, a.y);
    a.z = fmaf(s, w.z, a.z); a.w = fmaf(s, w.w, a.w);
}
__device__ __forceinline__ void add4(f4& a, const f4 b) {
    a.x += b.x; a.y += b.y; a.z += b.z; a.w += b.w;
}
__device__ __forceinline__ float dot4(const f4 a, const f4 b) {
    return fmaf(a.x, b.x, fmaf(a.y, b.y, fmaf(a.z, b.z, a.w * b.w)));
}

// ---------------- 32x32 tiled transpose (Wk only) ----------------
__global__ void transpose_kernel(const float* __restrict__ in, float* __restrict__ out,
                                 int R, int C, int ldin) {
    __shared__ float tile[32][33];
    int r0 = blockIdx.x * 32, c0 = blockIdx.y * 32;
    int tx = threadIdx.x & 31, ty = threadIdx.x >> 5;
#pragma unroll
    for (int k = 0; k < 4; ++k) {
        int r = r0 + ty + k * 8;
        tile[ty + k * 8][tx] = in[(size_t)r * ldin + c0 + tx];
    }
    __syncthreads();
#pragma unroll
    for (int k = 0; k < 4; ++k) {
        int c = c0 + ty + k * 8;
        out[(size_t)c * R + r0 + tx] = tile[tx][ty + k * 8];
    }
}

// ---------------- kpT[b][c][t] = sum_k enc[b*T+t][k] * WkT[k][c] ----------------
__global__ void __launch_bounds__(256) kproj_gemm_kernel(const float* __restrict__ A,
                                                         const float* __restrict__ Bt,
                                                         float* __restrict__ kpT) {
    __shared__ float As[64][68];
    __shared__ float Bs[64][64];
    int r0 = blockIdx.x * 64, c0 = blockIdx.y * 64;
    int tid = threadIdx.x;
    int tx = tid & 15, ty = tid >> 4;
    float acc[4][4] = {};
    for (int k0 = 0; k0 < 512; k0 += 64) {
#pragma unroll
        for (int i = 0; i < 4; ++i) {
            int row = i * 16 + ty, col = tx * 4;
            f4 av = *(const f4*)(A + (size_t)(r0 + row) * 512 + k0 + col);
            As[row][col] = av.x; As[row][col + 1] = av.y; As[row][col + 2] = av.z; As[row][col + 3] = av.w;
            f4 bv = *(const f4*)(Bt + (size_t)(k0 + row) * 512 + c0 + col);
            *(f4*)&Bs[row][col] = bv;
        }
        __syncthreads();
#pragma unroll 8
        for (int kk = 0; kk < 64; ++kk) {
            float a[4];
#pragma unroll
            for (int i = 0; i < 4; ++i) a[i] = As[ty * 4 + i][kk];
            f4 bv = *(const f4*)&Bs[kk][tx * 4];
#pragma unroll
            for (int i = 0; i < 4; ++i) {
                acc[i][0] += a[i] * bv.x; acc[i][1] += a[i] * bv.y;
                acc[i][2] += a[i] * bv.z; acc[i][3] += a[i] * bv.w;
            }
        }
        __syncthreads();
    }
#pragma unroll
    for (int i = 0; i < 4; ++i) {
        int r = r0 + ty * 4 + i;
        int b = r >> 7, t = r & 127;
#pragma unroll
        for (int j = 0; j < 4; ++j) {
            int c = c0 + tx * 4 + j;
            kpT[((size_t)b * H + c) * T + t] = acc[i][j];
        }
    }
}

// ---------------- persistent cooperative decoder ----------------
__global__ void __launch_bounds__(NTHR, 2) decoder_kernel(
    const float* __restrict__ enc, const float* __restrict__ hidden,
    const float* __restrict__ target, const float* __restrict__ Wq,
    const float* __restrict__ wv, const float* __restrict__ emb_W,
    const float* __restrict__ emb_b, const float* __restrict__ Wi0,
    const float* __restrict__ Wh0, const float* __restrict__ bi0,
    const float* __restrict__ bh0, const float* __restrict__ Wi1,
    const float* __restrict__ Wh1, const float* __restrict__ bi1,
    const float* __restrict__ bh1, const float* __restrict__ last_W,
    const float* __restrict__ last_b, const int* __restrict__ tmask,
    const float* __restrict__ kpT,
    float* __restrict__ out, float* __restrict__ out_hidden, float* __restrict__ out_attn,
    float* __restrict__ h0buf, float* __restrict__ h1buf,
    float* __restrict__ gi_emb, float* __restrict__ gi_ctx,
    float* __restrict__ ctxbuf, float* __restrict__ fbuf, float* __restrict__ inpbuf) {
    cg::grid_group grid = cg::this_grid();
    __shared__ __align__(16) float smem[16384];  // 64 KB
    f4* smem4 = (f4*)smem;
    const int tid = threadIdx.x, bid = blockIdx.x;

    // ---- PH0: init ----
    if (bid < 8) {
        ((f4*)h0buf)[bid * 512 + tid] = ((const f4*)hidden)[bid * 512 + tid];
    } else if (bid < 16) {
        int idx = (bid - 8) * 512 + tid;
        ((f4*)h1buf)[idx] = ((const f4*)(hidden + BH))[idx];
    } else if (bid == 16) {
        const f4* row = (const f4*)(emb_W + (size_t)tid * ODIM);
        float acc = emb_b[tid];
#pragma unroll 8
        for (int o = 0; o < 64; ++o) { f4 v = row[o]; acc += v.x + v.y + v.z + v.w; }
        for (int b = 0; b < B; ++b) inpbuf[b * E + tid] = acc;
    }
    grid.sync();

    int p0 = 0, p1 = 0;
    for (int i = 0; i < STEPS; ++i) {
        const float* h1cur = h1buf + (size_t)p1 * BH;
        // ======== PH_A: attention (blocks 0..31) + lin(i-1) (blocks 32..35) ========
        if (bid < 32) {
            int b = bid;
            float* hB = smem;            // 512
            float* qv = smem + 512;      // 512
            float* wvs = smem + 1024;    // 512
            float* sw = smem + 1536;     // 128
            float* red = smem + 1664;    // 8
            float* part = smem + 1792;   // 512
            f4* part4 = (f4*)(smem + 2304);  // 2048 floats
            if (tid < 128) {
                ((f4*)hB)[tid] = ((const f4*)(h1cur + (size_t)b * H))[tid];
                ((f4*)wvs)[tid] = ((const f4*)wv)[tid];
            }
            __syncthreads();
            {   // qproj: thread = j
                const f4* w = (const f4*)(Wq + (size_t)tid * H);
                float acc = 0.f;
#pragma unroll 8
                for (int kq = 0; kq < 128; ++kq) acc += dot4(w[kq], ((f4*)hB)[kq]);
                qv[tid] = acc;
            }
            __syncthreads();
            {   // scores
                int t = tid & 127, js = tid >> 7;
                const float* kp = kpT + ((size_t)b * H + js * 128) * T + t;
                float sa = 0.f;
#pragma unroll 4
                for (int jj = 0; jj < 128; ++jj)
                    sa += tanh_fast(qv[js * 128 + jj] + kp[(size_t)jj * T]) * wvs[js * 128 + jj];
                part[tid] = sa;
            }
            __syncthreads();
            if (tid < 128) {
                float sc = part[tid] + part[128 + tid] + part[256 + tid] + part[384 + tid];
                part[tid] = sc;
                float m = sc;
                for (int off = 32; off; off >>= 1) m = fmaxf(m, __shfl_xor(m, off));
                if ((tid & 63) == 0) red[tid >> 6] = m;
            }
            __syncthreads();
            if (tid < 128) {
                float M = fmaxf(red[0], red[1]);
                float e = __expf(part[tid] - M);
                sw[tid] = e;
                float s = e;
                for (int off = 32; off; off >>= 1) s += __shfl_xor(s, off);
                if ((tid & 63) == 0) red[4 + (tid >> 6)] = s;
            }
            __syncthreads();
            if (tid < 128) {
                float w_ = sw[tid] / (red[4] + red[5]);
                sw[tid] = w_;
                out_attn[((size_t)i * B + b) * T + tid] = w_;
            }
            __syncthreads();
            {   // ctx
                int cq = tid & 127, th = tid >> 7;
                const f4* e4 = (const f4*)(enc + (size_t)b * T * H);
                f4 acc = {0, 0, 0, 0};
                int t0 = th * 32;
#pragma unroll 8
                for (int t2 = t0; t2 < t0 + 32; ++t2) fma4(acc, sw[t2], e4[(size_t)t2 * 128 + cq]);
                part4[tid] = acc;
            }
            __syncthreads();
            if (tid < 128) {
                f4 s = part4[tid];
                add4(s, part4[128 + tid]); add4(s, part4[256 + tid]); add4(s, part4[384 + tid]);
                ((f4*)(ctxbuf + (size_t)b * H))[tid] = s;
            }
        } else if (bid < 36) {
            if (i > 0) {  // lin for step i-1
                int s = i - 1, ob0 = (bid - 32) * 64;
#pragma unroll
                for (int r = 0; r < 8; ++r) smem4[r * 512 + tid] = ((const f4*)h1cur)[r * 512 + tid];
                __syncthreads();
                int o = ob0 + (tid & 63), b8 = tid >> 6;
                const f4* w = (const f4*)(last_W + (size_t)o * H);
                f4 acc = {0, 0, 0, 0};
#pragma unroll 4
                for (int kq = 0; kq < 128; ++kq) {
                    f4 wv_ = w[kq];
                    acc.x += dot4(wv_, smem4[(b8 * 4 + 0) * 128 + kq]);
                    acc.y += dot4(wv_, smem4[(b8 * 4 + 1) * 128 + kq]);
                    acc.z += dot4(wv_, smem4[(b8 * 4 + 2) * 128 + kq]);
                    acc.w += dot4(wv_, smem4[(b8 * 4 + 3) * 128 + kq]);
                }
                float lb = last_b[o];
                float av[4] = {acc.x, acc.y, acc.z, acc.w};
#pragma unroll
                for (int ii = 0; ii < 4; ++ii) {
                    int b = b8 * 4 + ii;
                    float lin = av[ii] + lb;
                    float ff = tmask[s * B + b] ? target[((size_t)s * B + b) * ODIM + o] : lin;
                    fbuf[b * ODIM + o] = ff;
                    out[((size_t)s * B + b) * ODIM + o] = ff;
                }
            }
        }
        grid.sync();
        // ======== PH_B: gi_ctx (0..95) + emb(i-1) (96..103) + gi_emb0 (104..199, i==0) ========
        if (bid < 96) {
            int c0 = bid * 16;
#pragma unroll
            for (int r = 0; r < 8; ++r) smem4[r * 512 + tid] = ((const f4*)ctxbuf)[r * 512 + tid];
            __syncthreads();
            int c = c0 + (tid & 15), b = tid >> 4;
            const f4* w = (const f4*)(Wi0 + (size_t)c * 1024);
            float acc = bi0[c];
#pragma unroll 8
            for (int kq = 0; kq < 128; ++kq) acc += dot4(w[kq], smem4[b * 128 + kq]);
            gi_ctx[(size_t)b * G3 + c] = acc;
        } else if (bid < 104) {
            if (i > 0) {  // emb of forced(i-1) -> inpbuf
                int e0 = (bid - 96) * 64;
#pragma unroll
                for (int r = 0; r < 4; ++r) smem4[r * 512 + tid] = ((const f4*)fbuf)[r * 512 + tid];
                __syncthreads();
                int e = e0 + (tid & 63), b8 = tid >> 6;
                const f4* w = (const f4*)(emb_W + (size_t)e * ODIM);
                f4 acc = {0, 0, 0, 0};
#pragma unroll 8
                for (int oq = 0; oq < 64; ++oq) {
                    f4 wv_ = w[oq];
                    acc.x += dot4(wv_, smem4[(b8 * 4 + 0) * 64 + oq]);
                    acc.y += dot4(wv_, smem4[(b8 * 4 + 1) * 64 + oq]);
                    acc.z += dot4(wv_, smem4[(b8 * 4 + 2) * 64 + oq]);
                    acc.w += dot4(wv_, smem4[(b8 * 4 + 3) * 64 + oq]);
                }
                float eb = emb_b[e];
                float av[4] = {acc.x, acc.y, acc.z, acc.w};
#pragma unroll
                for (int ii = 0; ii < 4; ++ii) inpbuf[(size_t)(b8 * 4 + ii) * E + e] = av[ii] + eb;
            }
        } else if (bid < 200) {
            if (i == 0) {  // gi_emb slot 0 from inp0
                int c0 = (bid - 104) * 16;
#pragma unroll
                for (int r = 0; r < 8; ++r) smem4[r * 512 + tid] = ((const f4*)inpbuf)[r * 512 + tid];
                __syncthreads();
                int c = c0 + (tid & 15), b = tid >> 4;
                const f4* w = (const f4*)(Wi0 + (size_t)c * 1024 + 512);
                float acc = 0.f;
#pragma unroll 8
                for (int kq = 0; kq < 128; ++kq) acc += dot4(w[kq], smem4[b * 128 + kq]);
                gi_emb[(size_t)b * G3 + c] = acc;
            }
        }
        grid.sync();
        // ======== cells: phase t = 0..i+1 : l0(t) blocks 0..63, l1(t-1) blocks 64..191 ========
        for (int t = 0; t <= i + 1; ++t) {
            bool do0 = (t <= i), do1 = (t >= 1);
            const float* h0s = h0buf + (size_t)p0 * BH;
            const float* h1s = h1buf + (size_t)p1 * BH;
            float* h0d = h0buf + (size_t)(p0 ^ 1) * BH;
            float* h1d = h1buf + (size_t)(p1 ^ 1) * BH;
            if (bid < 64) {
                if (do0) {
                    int j0 = bid * 8;
#pragma unroll
                    for (int r = 0; r < 8; ++r) smem4[r * 512 + tid] = ((const f4*)h0s)[r * 512 + tid];
                    __syncthreads();
                    int j = tid & 7, b = (tid >> 3) & 31, kh = tid >> 8;
                    int jg = j0 + j;
                    const f4* wr = (const f4*)(Wh0 + (size_t)jg * H) + kh * 64;
                    const f4* wz = (const f4*)(Wh0 + (size_t)(H + jg) * H) + kh * 64;
                    const f4* wn = (const f4*)(Wh0 + (size_t)(2 * H + jg) * H) + kh * 64;
                    const f4* hv = smem4 + b * 128 + kh * 64;
                    float ar = 0.f, az = 0.f, an = 0.f;
#pragma unroll 4
                    for (int kq = 0; kq < 64; ++kq) {
                        f4 h = hv[kq];
                        ar += dot4(wr[kq], h); az += dot4(wz[kq], h); an += dot4(wn[kq], h);
                    }
                    __syncthreads();
                    float* part = smem;  // alias stage (reads done)
                    part[tid * 3 + 0] = ar; part[tid * 3 + 1] = az; part[tid * 3 + 2] = an;
                    __syncthreads();
                    if (tid < 256) {
                        int jj = tid & 7, bb = tid >> 3;
                        int jg2 = j0 + jj;
                        float gr = part[tid * 3 + 0] + part[(tid + 256) * 3 + 0] + bh0[jg2];
                        float gz = part[tid * 3 + 1] + part[(tid + 256) * 3 + 1] + bh0[H + jg2];
                        float gn = part[tid * 3 + 2] + part[(tid + 256) * 3 + 2] + bh0[2 * H + jg2];
                        const float* gc = gi_ctx + (size_t)bb * G3;
                        const float* ge = gi_emb + ((size_t)t * B + bb) * G3;
                        float rr = sigmoidf_(gc[jg2] + ge[jg2] + gr);
                        float zz = sigmoidf_(gc[H + jg2] + ge[H + jg2] + gz);
                        float nn = tanh_fast(gc[2 * H + jg2] + ge[2 * H + jg2] + rr * gn);
                        float hprev = h0s[(size_t)bb * H + jg2];
                        h0d[(size_t)bb * H + jg2] = (1.f - zz) * nn + zz * hprev;
                    }
                }
            } else if (bid < 192) {
                if (do1) {
                    int lb = bid - 64;
                    int j0 = (lb >> 1) * 8, b0 = (lb & 1) * 16;
                    const f4* xs = (const f4*)(h0s + (size_t)b0 * H);
                    const f4* hs = (const f4*)(h1s + (size_t)b0 * H);
#pragma unroll
                    for (int r = 0; r < 4; ++r) {
                        smem4[r * 512 + tid] = xs[r * 512 + tid];
                        smem4[2048 + r * 512 + tid] = hs[r * 512 + tid];
                    }
                    __syncthreads();
                    int j = tid & 7, b16 = (tid >> 3) & 15, m = (tid >> 7) & 1, kh = tid >> 8;
                    int jg = j0 + j;
                    const float* Wm = m ? Wh1 : Wi1;
                    const f4* base = smem4 + (m ? 2048 : 0) + b16 * 128 + kh * 64;
                    const f4* w0 = (const f4*)(Wm + (size_t)jg * H) + kh * 64;
                    const f4* w1 = (const f4*)(Wm + (size_t)(H + jg) * H) + kh * 64;
                    const f4* w2 = (const f4*)(Wm + (size_t)(2 * H + jg) * H) + kh * 64;
                    float a0 = 0.f, a1 = 0.f, a2 = 0.f;
#pragma unroll 4
                    for (int kq = 0; kq < 64; ++kq) {
                        f4 v = base[kq];
                        a0 += dot4(w0[kq], v); a1 += dot4(w1[kq], v); a2 += dot4(w2[kq], v);
                    }
                    __syncthreads();
                    float* part = smem;  // alias stage
                    part[tid * 3 + 0] = a0; part[tid * 3 + 1] = a1; part[tid * 3 + 2] = a2;
                    __syncthreads();
                    if (tid < 128) {
                        int jj = tid & 7, bb = tid >> 3;
                        int jg2 = j0 + jj;
                        float si0 = part[tid * 3 + 0] + part[(tid + 256) * 3 + 0] + bi1[jg2];
                        float si1 = part[tid * 3 + 1] + part[(tid + 256) * 3 + 1] + bi1[H + jg2];
                        float si2 = part[tid * 3 + 2] + part[(tid + 256) * 3 + 2] + bi1[2 * H + jg2];
                        float sh0 = part[(tid + 128) * 3 + 0] + part[(tid + 384) * 3 + 0] + bh1[jg2];
                        float sh1 = part[(tid + 128) * 3 + 1] + part[(tid + 384) * 3 + 1] + bh1[H + jg2];
                        float sh2 = part[(tid + 128) * 3 + 2] + part[(tid + 384) * 3 + 2] + bh1[2 * H + jg2];
                        float rr = sigmoidf_(si0 + sh0);
                        float zz = sigmoidf_(si1 + sh1);
                        float nn = tanh_fast(si2 + rr * sh2);
                        float hprev = h1s[(size_t)(b0 + bb) * H + jg2];
                        h1d[(size_t)(b0 + bb) * H + jg2] = (1.f - zz) * nn + zz * hprev;
                    }
                } else if (t == 0 && i >= 1 && bid < 160) {
                    // gi_emb slot i from inpbuf (l1 idle at t==0)
                    int c0 = (bid - 64) * 16;
#pragma unroll
                    for (int r = 0; r < 8; ++r) smem4[r * 512 + tid] = ((const f4*)inpbuf)[r * 512 + tid];
                    __syncthreads();
                    int c = c0 + (tid & 15), b = tid >> 4;
                    const f4* w = (const f4*)(Wi0 + (size_t)c * 1024 + 512);
                    float acc = 0.f;
#pragma unroll 8
                    for (int kq = 0; kq < 128; ++kq) acc += dot4(w[kq], smem4[b * 128 + kq]);
                    gi_emb[((size_t)i * B + b) * G3 + c] = acc;
                }
            }
            if (do0) p0 ^= 1;
            if (do1) p1 ^= 1;
            grid.sync();
        }
    }
    // ---- final: lin(15) + copy hidden out ----
    if (bid < 16) {
        int idx = bid * 512 + tid;
        f4 v = (idx < 4096) ? ((const f4*)(h0buf + (size_t)p0 * BH))[idx]
                            : ((const f4*)(h1buf + (size_t)p1 * BH))[idx - 4096];
        ((f4*)out_hidden)[idx] = v;
    } else if (bid >= 32 && bid < 36) {
        const float* h1cur = h1buf + (size_t)p1 * BH;
        int s = 15, ob0 = (bid - 32) * 64;
#pragma unroll
        for (int r = 0; r < 8; ++r) smem4[r * 512 + tid] = ((const f4*)h1cur)[r * 512 + tid];
        __syncthreads();
        int o = ob0 + (tid & 63), b8 = tid >> 6;
        const f4* w = (const f4*)(last_W + (size_t)o * H);
        f4 acc = {0, 0, 0, 0};
#pragma unroll 4
        for (int kq = 0; kq < 128; ++kq) {
            f4 wv_ = w[kq];
            acc.x += dot4(wv_, smem4[(b8 * 4 + 0) * 128 + kq]);
            acc.y += dot4(wv_, smem4[(b8 * 4 + 1) * 128 + kq]);
            acc.z += dot4(wv_, smem4[(b8 * 4 + 2) * 128 + kq]);
            acc.w += dot4(wv_, smem4[(b8 * 4 + 3) * 128 + kq]);
        }
        float lb = last_b[o];
        float av[4] = {acc.x, acc.y, acc.z, acc.w};
#pragma unroll
        for (int ii = 0; ii < 4; ++ii) {
            int b = b8 * 4 + ii;
            float lin = av[ii] + lb;
            float ff = tmask[s * B + b] ? target[((size_t)s * B + b) * ODIM + o] : lin;
            out[((size_t)s * B + b) * ODIM + o] = ff;
        }
    }
}

extern "C" void kernel_launch(void* const* d_in, const int* in_sizes, int n_in,
                              void* d_out_v, int out_size, void* d_ws, size_t ws_size,
                              hipStream_t stream) {
    const float* enc = (const float*)d_in[0];
    const float* hidden = (const float*)d_in[1];
    const float* target = (const float*)d_in[2];
    const float* Wq = (const float*)d_in[3];
    const float* Wk = (const float*)d_in[4];
    const float* wv = (const float*)d_in[5];
    const float* emb_W = (const float*)d_in[6];
    const float* emb_b = (const float*)d_in[7];
    const float* Wi0 = (const float*)d_in[8];
    const float* Wh0 = (const float*)d_in[9];
    const float* bi0 = (const float*)d_in[10];
    const float* bh0 = (const float*)d_in[11];
    const float* Wi1 = (const float*)d_in[12];
    const float* Wh1 = (const float*)d_in[13];
    const float* bi1 = (const float*)d_in[14];
    const float* bh1 = (const float*)d_in[15];
    const float* last_W = (const float*)d_in[16];
    const float* last_b = (const float*)d_in[17];
    const int* tmask = (const int*)d_in[18];

    float* out = (float*)d_out_v;
    float* out_hidden = out + (size_t)STEPS * B * ODIM;
    float* out_attn = out_hidden + (size_t)2 * BH;

    float* ws = (float*)d_ws;
    float* kpT = ws;                      // 2,097,152
    float* WkT = kpT + 2097152;           // 262,144
    float* gi_emb = WkT + 262144;         // 786,432
    float* gi_ctx = gi_emb + 786432;      // 49,152
    float* h0buf = gi_ctx + 49152;        // 32,768
    float* h1buf = h0buf + 32768;         // 32,768
    float* ctxbuf = h1buf + 32768;        // 16,384
    float* fbuf = ctxbuf + 16384;         // 8,192
    float* inpbuf = fbuf + 8192;          // 16,384

    transpose_kernel<<<dim3(16, 16), 256, 0, stream>>>(Wk, WkT, 512, 512, 512);
    kproj_gemm_kernel<<<dim3(64, 8), 256, 0, stream>>>(enc, WkT, kpT);

    const float* kpTc = kpT;
    void* args[] = {(void*)&enc,    (void*)&hidden, (void*)&target, (void*)&Wq,
                    (void*)&wv,     (void*)&emb_W,  (void*)&emb_b,  (void*)&Wi0,
                    (void*)&Wh0,    (void*)&bi0,    (void*)&bh0,    (void*)&Wi1,
                    (void*)&Wh1,    (void*)&bi1,    (void*)&bh1,    (void*)&last_W,
                    (void*)&last_b, (void*)&tmask,  (void*)&kpTc,   (void*)&out,
                    (void*)&out_hidden, (void*)&out_attn, (void*)&h0buf, (void*)&h1buf,
                    (void*)&gi_emb, (void*)&gi_ctx, (void*)&ctxbuf, (void*)&fbuf,
                    (void*)&inpbuf};
    hipLaunchCooperativeKernel((void*)decoder_kernel, dim3(NBLK), dim3(NTHR), args, 0, stream);
}

// Round 7
// 10834.056 us; speedup vs baseline: 1.2190x; 1.2190x over previous
//
#include <hip/hip_runtime.h>
#include <math.h>

#define B 32
#define T 128
#define H 512
#define E 512
#define ODIM 256
#define STEPS 16
#define G3 1536
#define BH (B * H)

typedef float4 f4;

__device__ __forceinline__ float sigmoidf_(float x) { return 1.0f / (1.0f + __expf(-x)); }
__device__ __forceinline__ float tanh_fast(float x) {
    float t = __expf(-2.0f * fabsf(x));
    float r = (1.0f - t) / (1.0f + t);
    return __builtin_copysignf(r, x);
}
__device__ __forceinline__ float dot4(const f4 a, const f4 b) {
    return fmaf(a.x, b.x, fmaf(a.y, b.y, fmaf(a.z, b.z, a.w * b.w)));
}

// ---- XOR-swizzled [kq][b] activation stage: conflict-free for kq-fast writes AND b-fast reads ----
__device__ __forceinline__ void stage_b32(const float* __restrict__ src, float* __restrict__ st,
                                          int tid, int nthr) {
    f4* d = (f4*)st;
    const f4* s = (const f4*)src;
    for (int idx = tid; idx < 4096; idx += nthr) {
        int b = idx >> 7, kq = idx & 127;
        d[kq * 32 + (b ^ (kq & 31))] = s[idx];
    }
}
__device__ __forceinline__ f4 ldb32(const float* __restrict__ st, int kq, int b) {
    return ((const f4*)st)[kq * 32 + (b ^ (kq & 31))];
}
__device__ __forceinline__ void stage_b16(const float* __restrict__ src, float* __restrict__ st,
                                          int tid, int nthr) {
    f4* d = (f4*)st;
    const f4* s = (const f4*)src;
    for (int idx = tid; idx < 2048; idx += nthr) {
        int b = idx >> 7, kq = idx & 127;
        d[kq * 16 + (b ^ (kq & 15))] = s[idx];
    }
}
__device__ __forceinline__ f4 ldb16(const float* __restrict__ st, int kq, int b) {
    return ((const f4*)st)[kq * 16 + (b ^ (kq & 15))];
}

// ---------------- 32x32 tiled transpose (Wk only) ----------------
__global__ void transpose_kernel(const float* __restrict__ in, float* __restrict__ out,
                                 int R, int C, int ldin) {
    __shared__ float tile[32][33];
    int r0 = blockIdx.x * 32, c0 = blockIdx.y * 32;
    int tx = threadIdx.x & 31, ty = threadIdx.x >> 5;
#pragma unroll
    for (int k = 0; k < 4; ++k) {
        int r = r0 + ty + k * 8;
        tile[ty + k * 8][tx] = in[(size_t)r * ldin + c0 + tx];
    }
    __syncthreads();
#pragma unroll
    for (int k = 0; k < 4; ++k) {
        int c = c0 + ty + k * 8;
        out[(size_t)c * R + r0 + tx] = tile[tx][ty + k * 8];
    }
}

// ---------------- kpT[b][c][t] = sum_k enc[b*T+t][k] * WkT[k][c] ----------------
__global__ void __launch_bounds__(256) kproj_gemm_kernel(const float* __restrict__ A,
                                                         const float* __restrict__ Bt,
                                                         float* __restrict__ kpT) {
    __shared__ float As[64][68];
    __shared__ float Bs[64][64];
    int r0 = blockIdx.x * 64, c0 = blockIdx.y * 64;
    int tid = threadIdx.x;
    int tx = tid & 15, ty = tid >> 4;
    float acc[4][4] = {};
    for (int k0 = 0; k0 < 512; k0 += 64) {
#pragma unroll
        for (int i = 0; i < 4; ++i) {
            int row = i * 16 + ty, col = tx * 4;
            f4 av = *(const f4*)(A + (size_t)(r0 + row) * 512 + k0 + col);
            As[row][col] = av.x; As[row][col + 1] = av.y; As[row][col + 2] = av.z; As[row][col + 3] = av.w;
            f4 bv = *(const f4*)(Bt + (size_t)(k0 + row) * 512 + c0 + col);
            *(f4*)&Bs[row][col] = bv;
        }
        __syncthreads();
#pragma unroll 8
        for (int kk = 0; kk < 64; ++kk) {
            float a[4];
#pragma unroll
            for (int i = 0; i < 4; ++i) a[i] = As[ty * 4 + i][kk];
            f4 bv = *(const f4*)&Bs[kk][tx * 4];
#pragma unroll
            for (int i = 0; i < 4; ++i) {
                acc[i][0] += a[i] * bv.x; acc[i][1] += a[i] * bv.y;
                acc[i][2] += a[i] * bv.z; acc[i][3] += a[i] * bv.w;
            }
        }
        __syncthreads();
    }
#pragma unroll
    for (int i = 0; i < 4; ++i) {
        int r = r0 + ty * 4 + i;
        int b = r >> 7, t = r & 127;
#pragma unroll
        for (int j = 0; j < 4; ++j) {
            int c = c0 + tx * 4 + j;
            kpT[((size_t)b * H + c) * T + t] = acc[i][j];
        }
    }
}

// ---------------- init: copy hidden; block 0 computes inp0 = emb(ones)*SOS ----------------
__global__ void __launch_bounds__(512) init_kernel(const float* __restrict__ hidden,
                                                   const float* __restrict__ emb_W,
                                                   const float* __restrict__ emb_b,
                                                   float* __restrict__ h0, float* __restrict__ h1,
                                                   float* __restrict__ inp) {
    int b = blockIdx.x, tid = threadIdx.x;
    h0[b * H + tid] = hidden[b * H + tid];
    h1[b * H + tid] = hidden[BH + b * H + tid];
    if (b == 0) {
        const f4* row = (const f4*)(emb_W + (size_t)tid * ODIM);
        float acc = emb_b[tid];
#pragma unroll 8
        for (int o = 0; o < 64; ++o) { f4 v = row[o]; acc += v.x + v.y + v.z + v.w; }
        for (int bb = 0; bb < B; ++bb) inp[bb * E + tid] = acc;
    }
}

// ---------------- attn1: qproj (blocks<nb_q: 64 x 8j, all b) + lin(prev) (32 x 8o, all b) ----------------
__global__ void __launch_bounds__(256) attn1_kernel(
    int nb_q, const float* __restrict__ h1cur, const float* __restrict__ Wq,
    float* __restrict__ q, const float* __restrict__ last_W, const float* __restrict__ last_b,
    const float* __restrict__ target_step, const int* __restrict__ mask_step,
    float* __restrict__ f, float* __restrict__ out_step) {
    __shared__ float sh[16384];
    int tid = threadIdx.x;
    stage_b32(h1cur, sh, tid, 256);
    __syncthreads();
    if ((int)blockIdx.x < nb_q) {
        int jg = blockIdx.x * 8 + (tid & 7), b = tid >> 3;
        const f4* w = (const f4*)(Wq + (size_t)jg * H);
        float acc = 0.f;
#pragma unroll 8
        for (int kq = 0; kq < 128; ++kq) acc += dot4(w[kq], ldb32(sh, kq, b));
        q[b * H + jg] = acc;
    } else {
        int og = (blockIdx.x - nb_q) * 8 + (tid & 7), b = tid >> 3;
        const f4* w = (const f4*)(last_W + (size_t)og * H);
        float acc = 0.f;
#pragma unroll 8
        for (int kq = 0; kq < 128; ++kq) acc += dot4(w[kq], ldb32(sh, kq, b));
        float lin = acc + last_b[og];
        float ff = mask_step[b] ? target_step[b * ODIM + og] : lin;
        f[b * ODIM + og] = ff;
        out_step[b * ODIM + og] = ff;
    }
}

// ---------------- attn2: scores partials (256 blk: 32b x 8js) + emb(prev) (32 blk: 16e) ----------------
__global__ void __launch_bounds__(256) attn2_kernel(
    const float* __restrict__ q, const float* __restrict__ kpT, const float* __restrict__ wv,
    float* __restrict__ spart, const float* __restrict__ f, const float* __restrict__ emb_W,
    const float* __restrict__ emb_b, float* __restrict__ inp) {
    __shared__ float sm[8704];
    int tid = threadIdx.x;
    if ((int)blockIdx.x < 256) {
        int b = blockIdx.x >> 3, js = blockIdx.x & 7;
        float* qs = sm;        // 64
        float* ws_ = sm + 64;  // 64
        float* part = sm + 128;  // 256
        if (tid < 64) {
            qs[tid] = q[b * H + js * 64 + tid];
            ws_[tid] = wv[js * 64 + tid];
        }
        __syncthreads();
        int t = tid & 127, jh = tid >> 7;
        const float* kp = kpT + ((size_t)b * H + js * 64 + jh * 32) * T + t;
        float sa = 0.f;
#pragma unroll 8
        for (int jj = 0; jj < 32; ++jj) {
            int j = jh * 32 + jj;
            sa += tanh_fast(qs[j] + kp[(size_t)jj * T]) * ws_[j];
        }
        part[tid] = sa;
        __syncthreads();
        if (tid < 128) spart[((size_t)b * 8 + js) * T + tid] = part[tid] + part[128 + tid];
    } else {
        // emb of forced(i-1): stage f [64oq][32] swizzled (32 KB)
        float* st = sm;
        {
            f4* d = (f4*)st;
            const f4* s = (const f4*)f;
            for (int idx = tid; idx < 2048; idx += 256) {
                int b = idx >> 6, oq = idx & 63;
                d[oq * 32 + (b ^ (oq & 31))] = s[idx];
            }
        }
        __syncthreads();
        int eg = (blockIdx.x - 256) * 16 + (tid & 15), bq = tid >> 4;
        const f4* w = (const f4*)(emb_W + (size_t)eg * ODIM);
        float a0 = 0.f, a1 = 0.f;
#pragma unroll 4
        for (int oq = 0; oq < 64; ++oq) {
            f4 wv_ = w[oq];
            a0 += dot4(wv_, ((const f4*)st)[oq * 32 + (bq ^ (oq & 31))]);
            a1 += dot4(wv_, ((const f4*)st)[oq * 32 + ((bq + 16) ^ (oq & 31))]);
        }
        float eb = emb_b[eg];
        inp[bq * E + eg] = a0 + eb;
        inp[(bq + 16) * E + eg] = a1 + eb;
    }
}

// ---------------- attn3: softmax (redundant per c-slice) + ctx (256 blk: 32b x 8cs) ----------------
__global__ void __launch_bounds__(256) attn3_kernel(
    const float* __restrict__ spart, const float* __restrict__ enc,
    float* __restrict__ ctx, float* __restrict__ attn_out) {
    __shared__ float sw[T];
    __shared__ float red[4];
    __shared__ float part[256];
    int tid = threadIdx.x;
    int b = blockIdx.x >> 3, cs = blockIdx.x & 7;
    float sv = 0.f;
    if (tid < 128) {
        const float* sp = spart + (size_t)b * 8 * T + tid;
#pragma unroll
        for (int js = 0; js < 8; ++js) sv += sp[js * T];
        float m = sv;
        for (int off = 32; off; off >>= 1) m = fmaxf(m, __shfl_xor(m, off));
        if ((tid & 63) == 0) red[tid >> 6] = m;
    }
    __syncthreads();
    if (tid < 128) {
        float M = fmaxf(red[0], red[1]);
        float e = __expf(sv - M);
        sw[tid] = e;
        float s = e;
        for (int off = 32; off; off >>= 1) s += __shfl_xor(s, off);
        if ((tid & 63) == 0) red[2 + (tid >> 6)] = s;
    }
    __syncthreads();
    if (tid < 128) {
        float w = sw[tid] / (red[2] + red[3]);
        sw[tid] = w;
        if (cs == 0) attn_out[(size_t)b * T + tid] = w;
    }
    __syncthreads();
    int c = tid & 63, tq = tid >> 6;
    int cg = cs * 64 + c;
    const float* ep = enc + ((size_t)b * T + tq * 32) * H + cg;
    float acc = 0.f;
#pragma unroll 8
    for (int t2 = 0; t2 < 32; ++t2) acc += sw[tq * 32 + t2] * ep[(size_t)t2 * H];
    part[tid] = acc;
    __syncthreads();
    if (tid < 64) ctx[(size_t)b * H + cg] = part[tid] + part[64 + tid] + part[128 + tid] + part[192 + tid];
}

// ---------------- gi: 96 blk gi_ctx (+bi0) | 96 blk gi_emb[i]; 16 c per block, all b ----------------
__global__ void __launch_bounds__(256) gi_kernel(
    const float* __restrict__ ctx, const float* __restrict__ inp,
    const float* __restrict__ Wi0, const float* __restrict__ bi0,
    float* __restrict__ gi_ctx, float* __restrict__ gi_emb_i) {
    __shared__ float sh[16384];
    int tid = threadIdx.x;
    bool isC = (int)blockIdx.x < 96;
    int lb = isC ? blockIdx.x : blockIdx.x - 96;
    stage_b32(isC ? ctx : inp, sh, tid, 256);
    __syncthreads();
    int cg = lb * 16 + (tid & 15), bq = tid >> 4;
    const f4* w = (const f4*)(Wi0 + (size_t)cg * (E + H) + (isC ? 0 : H));
    float a0 = 0.f, a1 = 0.f;
#pragma unroll 4
    for (int kq = 0; kq < 128; ++kq) {
        f4 wv_ = w[kq];
        a0 += dot4(wv_, ldb32(sh, kq, bq));
        a1 += dot4(wv_, ldb32(sh, kq, bq + 16));
    }
    float bias = isC ? bi0[cg] : 0.f;
    float* dst = isC ? gi_ctx : gi_emb_i;
    dst[(size_t)bq * G3 + cg] = a0 + bias;
    dst[(size_t)(bq + 16) * G3 + cg] = a1 + bias;
}

// ---------------- fused dual GRU cell ----------------
// l0: blocks [0,nb0=64): 8j each, all 32 b (Wh0 read once)
// l1: blocks [nb0,nb0+128): (jsl=lb>>1)*8 j, b-half (lb&1)*16, thread m-split Wi1/Wh1
__global__ void __launch_bounds__(256) cell_kernel(
    int nb0, const float* __restrict__ h0_src, float* __restrict__ h0_dst,
    const float* __restrict__ h1_src, float* __restrict__ h1_dst,
    const float* __restrict__ gi_emb_t, const float* __restrict__ gi_ctx,
    const float* __restrict__ Wh0, const float* __restrict__ bh0,
    const float* __restrict__ Wi1, const float* __restrict__ bi1,
    const float* __restrict__ Wh1, const float* __restrict__ bh1) {
    __shared__ float sh[16384];
    int tid = threadIdx.x;
    if ((int)blockIdx.x < nb0) {
        stage_b32(h0_src, sh, tid, 256);
        __syncthreads();
        int j = tid & 7, b = tid >> 3, jg = blockIdx.x * 8 + j;
        const f4* wr = (const f4*)(Wh0 + (size_t)jg * H);
        const f4* wz = (const f4*)(Wh0 + (size_t)(H + jg) * H);
        const f4* wn = (const f4*)(Wh0 + (size_t)(2 * H + jg) * H);
        float ar = 0.f, az = 0.f, an = 0.f;
#pragma unroll 4
        for (int kq = 0; kq < 128; ++kq) {
            f4 h = ldb32(sh, kq, b);
            ar += dot4(wr[kq], h); az += dot4(wz[kq], h); an += dot4(wn[kq], h);
        }
        const float* gc = gi_ctx + (size_t)b * G3;
        const float* ge = gi_emb_t + (size_t)b * G3;
        float r = sigmoidf_(gc[jg] + ge[jg] + ar + bh0[jg]);
        float z = sigmoidf_(gc[H + jg] + ge[H + jg] + az + bh0[H + jg]);
        float n = tanh_fast(gc[2 * H + jg] + ge[2 * H + jg] + r * (an + bh0[2 * H + jg]));
        f4 hp = ldb32(sh, jg >> 2, b);
        float hprev = ((const float*)&hp)[jg & 3];
        h0_dst[(size_t)b * H + jg] = (1.f - z) * n + z * hprev;
    } else {
        int lb = blockIdx.x - nb0;
        int b0 = (lb & 1) * 16, j0 = (lb >> 1) * 8;
        float* stA = sh;          // x = y0(t-1), 32 KB
        float* stB = sh + 8192;   // h1, 32 KB
        stage_b16(h0_src + (size_t)b0 * H, stA, tid, 256);
        stage_b16(h1_src + (size_t)b0 * H, stB, tid, 256);
        __syncthreads();
        int j = tid & 7, b = (tid >> 3) & 15, m = tid >> 7;
        int jg = j0 + j;
        const float* Wm = m ? Wh1 : Wi1;
        const float* stm = m ? stB : stA;
        const f4* w0 = (const f4*)(Wm + (size_t)jg * H);
        const f4* w1 = (const f4*)(Wm + (size_t)(H + jg) * H);
        const f4* w2 = (const f4*)(Wm + (size_t)(2 * H + jg) * H);
        float a0 = 0.f, a1 = 0.f, a2 = 0.f;
#pragma unroll 4
        for (int kq = 0; kq < 128; ++kq) {
            f4 v = ldb16(stm, kq, b);
            a0 += dot4(w0[kq], v); a1 += dot4(w1[kq], v); a2 += dot4(w2[kq], v);
        }
        __syncthreads();
        if (m == 0) {  // alias partials onto stA (x fully consumed; m=1 never reads stA)
            float* p = stA + (b * 8 + j) * 3;
            p[0] = a0; p[1] = a1; p[2] = a2;
        }
        __syncthreads();
        if (m == 1) {
            const float* p = stA + (b * 8 + j) * 3;
            float r = sigmoidf_(p[0] + bi1[jg] + a0 + bh1[jg]);
            float z = sigmoidf_(p[1] + bi1[H + jg] + a1 + bh1[H + jg]);
            float n = tanh_fast(p[2] + bi1[2 * H + jg] + r * (a2 + bh1[2 * H + jg]));
            f4 hp = ldb16(stB, jg >> 2, b);
            float hprev = ((const float*)&hp)[jg & 3];
            h1_dst[(size_t)(b0 + b) * H + jg] = (1.f - z) * n + z * hprev;
        }
    }
}

__global__ void copy_hidden_kernel(const float* __restrict__ h0, const float* __restrict__ h1,
                                   float* __restrict__ dst) {
    int i = blockIdx.x * 256 + threadIdx.x;
    dst[i] = h0[i];
    dst[BH + i] = h1[i];
}

extern "C" void kernel_launch(void* const* d_in, const int* in_sizes, int n_in,
                              void* d_out_v, int out_size, void* d_ws, size_t ws_size,
                              hipStream_t stream) {
    const float* enc = (const float*)d_in[0];
    const float* hidden = (const float*)d_in[1];
    const float* target = (const float*)d_in[2];
    const float* Wq = (const float*)d_in[3];
    const float* Wk = (const float*)d_in[4];
    const float* wv = (const float*)d_in[5];
    const float* emb_W = (const float*)d_in[6];
    const float* emb_b = (const float*)d_in[7];
    const float* Wi0 = (const float*)d_in[8];
    const float* Wh0 = (const float*)d_in[9];
    const float* bi0 = (const float*)d_in[10];
    const float* bh0 = (const float*)d_in[11];
    const float* Wi1 = (const float*)d_in[12];
    const float* Wh1 = (const float*)d_in[13];
    const float* bi1 = (const float*)d_in[14];
    const float* bh1 = (const float*)d_in[15];
    const float* last_W = (const float*)d_in[16];
    const float* last_b = (const float*)d_in[17];
    const int* tmask = (const int*)d_in[18];

    float* out = (float*)d_out_v;
    float* out_hidden = out + (size_t)STEPS * B * ODIM;
    float* out_attn = out_hidden + (size_t)2 * BH;

    float* ws = (float*)d_ws;
    float* kpT = ws;                      // 2,097,152
    float* WkT = kpT + 2097152;           // 262,144
    float* gi_emb = WkT + 262144;         // 786,432
    float* gi_ctx = gi_emb + 786432;      // 49,152
    float* h0buf = gi_ctx + 49152;        // 32,768 (2x)
    float* h1buf = h0buf + 32768;         // 32,768 (2x)
    float* qbuf = h1buf + 32768;          // 16,384
    float* ctxbuf = qbuf + 16384;         // 16,384
    float* fbuf = ctxbuf + 16384;         // 8,192
    float* inpbuf = fbuf + 8192;          // 16,384
    float* spart = inpbuf + 16384;        // 32,768

    transpose_kernel<<<dim3(16, 16), 256, 0, stream>>>(Wk, WkT, 512, 512, 512);
    kproj_gemm_kernel<<<dim3(64, 8), 256, 0, stream>>>(enc, WkT, kpT);
    init_kernel<<<B, 512, 0, stream>>>(hidden, emb_W, emb_b, h0buf, h1buf, inpbuf);

    int p0 = 0, p1 = 0;
    for (int i = 0; i < STEPS; ++i) {
        int im1 = (i > 0) ? i - 1 : 0;
        const float* h1cur = h1buf + (size_t)p1 * BH;
        attn1_kernel<<<(i > 0) ? 96 : 64, 256, 0, stream>>>(
            64, h1cur, Wq, qbuf, last_W, last_b, target + (size_t)im1 * B * ODIM,
            tmask + im1 * B, fbuf, out + (size_t)im1 * B * ODIM);
        attn2_kernel<<<(i > 0) ? 288 : 256, 256, 0, stream>>>(qbuf, kpT, wv, spart, fbuf,
                                                              emb_W, emb_b, inpbuf);
        attn3_kernel<<<256, 256, 0, stream>>>(spart, enc, ctxbuf, out_attn + (size_t)i * B * T);
        gi_kernel<<<192, 256, 0, stream>>>(ctxbuf, inpbuf, Wi0, bi0, gi_ctx,
                                           gi_emb + (size_t)i * B * G3);
        for (int t = 0; t <= i + 1; ++t) {
            int nb0 = (t <= i) ? 64 : 0;
            int nb1 = (t >= 1) ? 128 : 0;
            int tge = (t <= i) ? t : 0;  // unused when nb0==0
            cell_kernel<<<nb0 + nb1, 256, 0, stream>>>(
                nb0, h0buf + (size_t)p0 * BH, h0buf + (size_t)(p0 ^ 1) * BH,
                h1buf + (size_t)p1 * BH, h1buf + (size_t)(p1 ^ 1) * BH,
                gi_emb + (size_t)tge * B * G3, gi_ctx, Wh0, bh0, Wi1, bi1, Wh1, bh1);
            if (nb0) p0 ^= 1;
            if (nb1) p1 ^= 1;
        }
    }
    // final lin (step 15)
    attn1_kernel<<<32, 256, 0, stream>>>(0, h1buf + (size_t)p1 * BH, Wq, qbuf, last_W, last_b,
                                         target + (size_t)15 * B * ODIM, tmask + 15 * B, fbuf,
                                         out + (size_t)15 * B * ODIM);
    copy_hidden_kernel<<<64, 256, 0, stream>>>(h0buf + (size_t)p0 * BH, h1buf + (size_t)p1 * BH,
                                               out_hidden);
}

// Round 8
// 5592.234 us; speedup vs baseline: 2.3616x; 1.9373x over previous
//
#include <hip/hip_runtime.h>
#include <math.h>

#define B 32
#define T 128
#define H 512
#define E 512
#define ODIM 256
#define STEPS 16
#define G3 1536
#define BH (B * H)

typedef float4 f4;
typedef unsigned int uint32;
typedef unsigned short ushort;

__device__ __forceinline__ float sigmoidf_(float x) { return 1.0f / (1.0f + __expf(-x)); }
__device__ __forceinline__ float tanh_fast(float x) {
    float t = __expf(-2.0f * fabsf(x));
    float r = (1.0f - t) / (1.0f + t);
    return __builtin_copysignf(r, x);
}
__device__ __forceinline__ float dot4(const f4 a, const f4 b) {
    return fmaf(a.x, b.x, fmaf(a.y, b.y, fmaf(a.z, b.z, a.w * b.w)));
}
// bf16 pair (packed in u32) -> two floats (exact)
__device__ __forceinline__ void bf2x(uint32 v, float& lo, float& hi) {
    union { uint32 u; float f; } a, b;
    a.u = v << 16; b.u = v & 0xffff0000u;
    lo = a.f; hi = b.f;
}
__device__ __forceinline__ float dot8bf(uint4 wv, const f4 hA, const f4 hB) {
    float w0, w1, w2, w3, w4, w5, w6, w7;
    bf2x(wv.x, w0, w1); bf2x(wv.y, w2, w3); bf2x(wv.z, w4, w5); bf2x(wv.w, w6, w7);
    float s = fmaf(w0, hA.x, w1 * hA.y);
    s = fmaf(w2, hA.z, s); s = fmaf(w3, hA.w, s);
    s = fmaf(w4, hB.x, s); s = fmaf(w5, hB.y, s);
    s = fmaf(w6, hB.z, s); s = fmaf(w7, hB.w, s);
    return s;
}
__device__ __forceinline__ ushort f2bf(float f) {
    union { float f; uint32 u; } a; a.f = f;
    uint32 r = a.u + 0x7fffu + ((a.u >> 16) & 1u);
    return (ushort)(r >> 16);
}

// ---- XOR-swizzled [kq][b] activation stage (conflict-free both directions) ----
__device__ __forceinline__ void stage_b32(const float* __restrict__ src, float* __restrict__ st,
                                          int tid, int nthr) {
    f4* d = (f4*)st;
    const f4* s = (const f4*)src;
    for (int idx = tid; idx < 4096; idx += nthr) {
        int b = idx >> 7, kq = idx & 127;
        d[kq * 32 + (b ^ (kq & 31))] = s[idx];
    }
}
__device__ __forceinline__ f4 ldb32(const float* __restrict__ st, int kq, int b) {
    return ((const f4*)st)[kq * 32 + (b ^ (kq & 31))];
}
__device__ __forceinline__ void stage_b16(const float* __restrict__ src, float* __restrict__ st,
                                          int tid, int nthr) {
    f4* d = (f4*)st;
    const f4* s = (const f4*)src;
    for (int idx = tid; idx < 2048; idx += nthr) {
        int b = idx >> 7, kq = idx & 127;
        d[kq * 16 + (b ^ (kq & 15))] = s[idx];
    }
}
__device__ __forceinline__ f4 ldb16(const float* __restrict__ st, int kq, int b) {
    return ((const f4*)st)[kq * 16 + (b ^ (kq & 15))];
}

// ---------------- fp32 -> bf16 convert (n4 = n/4) ----------------
__global__ void cvt_bf16_kernel(const float* __restrict__ src, ushort* __restrict__ dst, int n4) {
    int i = blockIdx.x * 256 + threadIdx.x;
    if (i < n4) {
        f4 v = ((const f4*)src)[i];
        ushort4 o;
        o.x = f2bf(v.x); o.y = f2bf(v.y); o.z = f2bf(v.z); o.w = f2bf(v.w);
        ((ushort4*)dst)[i] = o;
    }
}

// ---------------- 32x32 tiled transpose (Wk only) ----------------
__global__ void transpose_kernel(const float* __restrict__ in, float* __restrict__ out,
                                 int R, int C, int ldin) {
    __shared__ float tile[32][33];
    int r0 = blockIdx.x * 32, c0 = blockIdx.y * 32;
    int tx = threadIdx.x & 31, ty = threadIdx.x >> 5;
#pragma unroll
    for (int k = 0; k < 4; ++k) {
        int r = r0 + ty + k * 8;
        tile[ty + k * 8][tx] = in[(size_t)r * ldin + c0 + tx];
    }
    __syncthreads();
#pragma unroll
    for (int k = 0; k < 4; ++k) {
        int c = c0 + ty + k * 8;
        out[(size_t)c * R + r0 + tx] = tile[tx][ty + k * 8];
    }
}

// ---------------- kpT[b][c][t] = sum_k enc[b*T+t][k] * WkT[k][c] ----------------
__global__ void __launch_bounds__(256) kproj_gemm_kernel(const float* __restrict__ A,
                                                         const float* __restrict__ Bt,
                                                         float* __restrict__ kpT) {
    __shared__ float As[64][68];
    __shared__ float Bs[64][64];
    int r0 = blockIdx.x * 64, c0 = blockIdx.y * 64;
    int tid = threadIdx.x;
    int tx = tid & 15, ty = tid >> 4;
    float acc[4][4] = {};
    for (int k0 = 0; k0 < 512; k0 += 64) {
#pragma unroll
        for (int i = 0; i < 4; ++i) {
            int row = i * 16 + ty, col = tx * 4;
            f4 av = *(const f4*)(A + (size_t)(r0 + row) * 512 + k0 + col);
            As[row][col] = av.x; As[row][col + 1] = av.y; As[row][col + 2] = av.z; As[row][col + 3] = av.w;
            f4 bv = *(const f4*)(Bt + (size_t)(k0 + row) * 512 + c0 + col);
            *(f4*)&Bs[row][col] = bv;
        }
        __syncthreads();
#pragma unroll 8
        for (int kk = 0; kk < 64; ++kk) {
            float a[4];
#pragma unroll
            for (int i = 0; i < 4; ++i) a[i] = As[ty * 4 + i][kk];
            f4 bv = *(const f4*)&Bs[kk][tx * 4];
#pragma unroll
            for (int i = 0; i < 4; ++i) {
                acc[i][0] += a[i] * bv.x; acc[i][1] += a[i] * bv.y;
                acc[i][2] += a[i] * bv.z; acc[i][3] += a[i] * bv.w;
            }
        }
        __syncthreads();
    }
#pragma unroll
    for (int i = 0; i < 4; ++i) {
        int r = r0 + ty * 4 + i;
        int b = r >> 7, t = r & 127;
#pragma unroll
        for (int j = 0; j < 4; ++j) {
            int c = c0 + tx * 4 + j;
            kpT[((size_t)b * H + c) * T + t] = acc[i][j];
        }
    }
}

// ---------------- init: copy hidden; block 0 computes inp0 = emb(ones)*SOS ----------------
__global__ void __launch_bounds__(512) init_kernel(const float* __restrict__ hidden,
                                                   const float* __restrict__ emb_W,
                                                   const float* __restrict__ emb_b,
                                                   float* __restrict__ h0, float* __restrict__ h1,
                                                   float* __restrict__ inp) {
    int b = blockIdx.x, tid = threadIdx.x;
    h0[b * H + tid] = hidden[b * H + tid];
    h1[b * H + tid] = hidden[BH + b * H + tid];
    if (b == 0) {
        const f4* row = (const f4*)(emb_W + (size_t)tid * ODIM);
        float acc = emb_b[tid];
#pragma unroll 8
        for (int o = 0; o < 64; ++o) { f4 v = row[o]; acc += v.x + v.y + v.z + v.w; }
        for (int bb = 0; bb < B; ++bb) inp[bb * E + tid] = acc;
    }
}

// ---------------- attn1: qproj (64 x 8j, all b) + lin(prev) (32 x 8o, all b) ----------------
__global__ void __launch_bounds__(256) attn1_kernel(
    int nb_q, const float* __restrict__ h1cur, const float* __restrict__ Wq,
    float* __restrict__ q, const float* __restrict__ last_W, const float* __restrict__ last_b,
    const float* __restrict__ target_step, const int* __restrict__ mask_step,
    float* __restrict__ f, float* __restrict__ out_step) {
    __shared__ float sh[16384];
    int tid = threadIdx.x;
    stage_b32(h1cur, sh, tid, 256);
    __syncthreads();
    if ((int)blockIdx.x < nb_q) {
        int jg = blockIdx.x * 8 + (tid & 7), b = tid >> 3;
        const f4* w = (const f4*)(Wq + (size_t)jg * H);
        float acc = 0.f;
#pragma unroll 8
        for (int kq = 0; kq < 128; ++kq) acc += dot4(w[kq], ldb32(sh, kq, b));
        q[b * H + jg] = acc;
    } else {
        int og = (blockIdx.x - nb_q) * 8 + (tid & 7), b = tid >> 3;
        const f4* w = (const f4*)(last_W + (size_t)og * H);
        float acc = 0.f;
#pragma unroll 8
        for (int kq = 0; kq < 128; ++kq) acc += dot4(w[kq], ldb32(sh, kq, b));
        float lin = acc + last_b[og];
        float ff = mask_step[b] ? target_step[b * ODIM + og] : lin;
        f[b * ODIM + og] = ff;
        out_step[b * ODIM + og] = ff;
    }
}

// ---------------- attn2: scores partials (256 blk) + emb(prev) (32 blk) ----------------
__global__ void __launch_bounds__(256) attn2_kernel(
    const float* __restrict__ q, const float* __restrict__ kpT, const float* __restrict__ wv,
    float* __restrict__ spart, const float* __restrict__ f, const float* __restrict__ emb_W,
    const float* __restrict__ emb_b, float* __restrict__ inp) {
    __shared__ float sm[8704];
    int tid = threadIdx.x;
    if ((int)blockIdx.x < 256) {
        int b = blockIdx.x >> 3, js = blockIdx.x & 7;
        float* qs = sm;
        float* ws_ = sm + 64;
        float* part = sm + 128;
        if (tid < 64) {
            qs[tid] = q[b * H + js * 64 + tid];
            ws_[tid] = wv[js * 64 + tid];
        }
        __syncthreads();
        int t = tid & 127, jh = tid >> 7;
        const float* kp = kpT + ((size_t)b * H + js * 64 + jh * 32) * T + t;
        float sa = 0.f;
#pragma unroll 8
        for (int jj = 0; jj < 32; ++jj) {
            int j = jh * 32 + jj;
            sa += tanh_fast(qs[j] + kp[(size_t)jj * T]) * ws_[j];
        }
        part[tid] = sa;
        __syncthreads();
        if (tid < 128) spart[((size_t)b * 8 + js) * T + tid] = part[tid] + part[128 + tid];
    } else {
        float* st = sm;
        {
            f4* d = (f4*)st;
            const f4* s = (const f4*)f;
            for (int idx = tid; idx < 2048; idx += 256) {
                int b = idx >> 6, oq = idx & 63;
                d[oq * 32 + (b ^ (oq & 31))] = s[idx];
            }
        }
        __syncthreads();
        int eg = (blockIdx.x - 256) * 16 + (tid & 15), bq = tid >> 4;
        const f4* w = (const f4*)(emb_W + (size_t)eg * ODIM);
        float a0 = 0.f, a1 = 0.f;
#pragma unroll 4
        for (int oq = 0; oq < 64; ++oq) {
            f4 wv_ = w[oq];
            a0 += dot4(wv_, ((const f4*)st)[oq * 32 + (bq ^ (oq & 31))]);
            a1 += dot4(wv_, ((const f4*)st)[oq * 32 + ((bq + 16) ^ (oq & 31))]);
        }
        float eb = emb_b[eg];
        inp[bq * E + eg] = a0 + eb;
        inp[(bq + 16) * E + eg] = a1 + eb;
    }
}

// ---------------- attn3: softmax + ctx (256 blk: 32b x 8cs) ----------------
__global__ void __launch_bounds__(256) attn3_kernel(
    const float* __restrict__ spart, const float* __restrict__ enc,
    float* __restrict__ ctx, float* __restrict__ attn_out) {
    __shared__ float sw[T];
    __shared__ float red[4];
    __shared__ float part[256];
    int tid = threadIdx.x;
    int b = blockIdx.x >> 3, cs = blockIdx.x & 7;
    float sv = 0.f;
    if (tid < 128) {
        const float* sp = spart + (size_t)b * 8 * T + tid;
#pragma unroll
        for (int js = 0; js < 8; ++js) sv += sp[js * T];
        float m = sv;
        for (int off = 32; off; off >>= 1) m = fmaxf(m, __shfl_xor(m, off));
        if ((tid & 63) == 0) red[tid >> 6] = m;
    }
    __syncthreads();
    if (tid < 128) {
        float M = fmaxf(red[0], red[1]);
        float e = __expf(sv - M);
        sw[tid] = e;
        float s = e;
        for (int off = 32; off; off >>= 1) s += __shfl_xor(s, off);
        if ((tid & 63) == 0) red[2 + (tid >> 6)] = s;
    }
    __syncthreads();
    if (tid < 128) {
        float w = sw[tid] / (red[2] + red[3]);
        sw[tid] = w;
        if (cs == 0) attn_out[(size_t)b * T + tid] = w;
    }
    __syncthreads();
    int c = tid & 63, tq = tid >> 6;
    int cg = cs * 64 + c;
    const float* ep = enc + ((size_t)b * T + tq * 32) * H + cg;
    float acc = 0.f;
#pragma unroll 8
    for (int t2 = 0; t2 < 32; ++t2) acc += sw[tq * 32 + t2] * ep[(size_t)t2 * H];
    part[tid] = acc;
    __syncthreads();
    if (tid < 64) ctx[(size_t)b * H + cg] = part[tid] + part[64 + tid] + part[128 + tid] + part[192 + tid];
}

// ---------------- gi (bf16 W): 96 blk gi_ctx (+bi0) | 96 blk gi_emb[i]; 16c, all b ----------------
__global__ void __launch_bounds__(256) gi_kernel(
    const float* __restrict__ ctx, const float* __restrict__ inp,
    const ushort* __restrict__ Wi0bf, const float* __restrict__ bi0,
    float* __restrict__ gi_ctx, float* __restrict__ gi_emb_i) {
    __shared__ float sh[16384];
    int tid = threadIdx.x;
    bool isC = (int)blockIdx.x < 96;
    int lb = isC ? blockIdx.x : blockIdx.x - 96;
    stage_b32(isC ? ctx : inp, sh, tid, 256);
    __syncthreads();
    int cg = lb * 16 + (tid & 15), bq = tid >> 4;
    const uint4* w = (const uint4*)(Wi0bf + (size_t)cg * 1024 + (isC ? 0 : 512));
    float a0 = 0.f, a1 = 0.f;
#pragma unroll 4
    for (int it = 0; it < 64; ++it) {
        uint4 wv = w[it];
        f4 hA0 = ldb32(sh, it * 2, bq), hB0 = ldb32(sh, it * 2 + 1, bq);
        f4 hA1 = ldb32(sh, it * 2, bq + 16), hB1 = ldb32(sh, it * 2 + 1, bq + 16);
        a0 += dot8bf(wv, hA0, hB0);
        a1 += dot8bf(wv, hA1, hB1);
    }
    float bias = isC ? bi0[cg] : 0.f;
    float* dst = isC ? gi_ctx : gi_emb_i;
    dst[(size_t)bq * G3 + cg] = a0 + bias;
    dst[(size_t)(bq + 16) * G3 + cg] = a1 + bias;
}

// ---------------- fused dual GRU cell, bf16 weights, deep k-split for MLP ----------------
// l0: blocks [0,nb0=256): 2j x 32b, threads (b32 x kh8)
// l1: blocks [nb0,nb0+256): 4j x 16b(half), threads (b16 x kh8 x m2)
__global__ void __launch_bounds__(256, 2) cell_kernel(
    int nb0, const float* __restrict__ h0_src, float* __restrict__ h0_dst,
    const float* __restrict__ h1_src, float* __restrict__ h1_dst,
    const float* __restrict__ gi_emb_t, const float* __restrict__ gi_ctx,
    const ushort* __restrict__ Wh0bf, const float* __restrict__ bh0,
    const ushort* __restrict__ Wi1bf, const float* __restrict__ bi1,
    const ushort* __restrict__ Wh1bf, const float* __restrict__ bh1) {
    __shared__ __align__(16) float sh[19456];  // 76 KB: 64KB stage + 12KB partials
    int tid = threadIdx.x;
    if ((int)blockIdx.x < nb0) {
        int j0 = blockIdx.x * 2;
        stage_b32(h0_src, sh, tid, 256);
        __syncthreads();
        int b = tid & 31, kh = tid >> 5;
        const uint4* wbase = (const uint4*)(Wh0bf + (size_t)kh * 64);
        // row (g,jj) at uint4 offset (g*1024 + j0 + jj)*64  [row stride 512 ushorts = 64 uint4]
        float acc[6] = {};
#pragma unroll 2
        for (int it = 0; it < 8; ++it) {
            f4 hA = ldb32(sh, kh * 16 + it * 2, b);
            f4 hB = ldb32(sh, kh * 16 + it * 2 + 1, b);
#pragma unroll
            for (int g = 0; g < 3; ++g)
#pragma unroll
                for (int jj = 0; jj < 2; ++jj) {
                    uint4 wv = wbase[((size_t)(g * 512 + j0 + jj)) * 64 + it];
                    acc[g * 2 + jj] += dot8bf(wv, hA, hB);
                }
        }
        float* part = sh + 16384;
#pragma unroll
        for (int r = 0; r < 6; ++r) part[tid * 6 + r] = acc[r];
        __syncthreads();
        if (tid < 64) {
            int fb = tid & 31, jj = tid >> 5;
            float s0 = 0.f, s1 = 0.f, s2 = 0.f;
#pragma unroll
            for (int k2 = 0; k2 < 8; ++k2) {
                const float* p = part + (k2 * 32 + fb) * 6;
                s0 += p[jj]; s1 += p[2 + jj]; s2 += p[4 + jj];
            }
            int jg = j0 + jj;
            const float* gc = gi_ctx + (size_t)fb * G3;
            const float* ge = gi_emb_t + (size_t)fb * G3;
            float r_ = sigmoidf_(gc[jg] + ge[jg] + s0 + bh0[jg]);
            float z_ = sigmoidf_(gc[H + jg] + ge[H + jg] + s1 + bh0[H + jg]);
            float n_ = tanh_fast(gc[2 * H + jg] + ge[2 * H + jg] + r_ * (s2 + bh0[2 * H + jg]));
            f4 hp = ldb32(sh, jg >> 2, fb);
            float hprev = ((const float*)&hp)[jg & 3];
            h0_dst[(size_t)fb * H + jg] = (1.f - z_) * n_ + z_ * hprev;
        }
    } else {
        int lb = blockIdx.x - nb0;
        int bh_ = lb & 1, js = lb >> 1;
        int j0 = js * 4, b0 = bh_ * 16;
        float* stX = sh;
        float* stH = sh + 8192;
        stage_b16(h0_src + (size_t)b0 * H, stX, tid, 256);
        stage_b16(h1_src + (size_t)b0 * H, stH, tid, 256);
        __syncthreads();
        int b = tid & 15, kh = (tid >> 4) & 7, m = tid >> 7;
        const ushort* Wm = m ? Wh1bf : Wi1bf;
        const float* stm = m ? stH : stX;
        const uint4* wbase = (const uint4*)(Wm + (size_t)kh * 64);
        float acc[12] = {};
#pragma unroll 1
        for (int it = 0; it < 8; ++it) {
            f4 hA = ldb16(stm, kh * 16 + it * 2, b);
            f4 hB = ldb16(stm, kh * 16 + it * 2 + 1, b);
#pragma unroll
            for (int g = 0; g < 3; ++g)
#pragma unroll
                for (int jj = 0; jj < 4; ++jj) {
                    uint4 wv = wbase[((size_t)(g * 512 + j0 + jj)) * 64 + it];
                    acc[g * 4 + jj] += dot8bf(wv, hA, hB);
                }
        }
        float* part = sh + 16384;
#pragma unroll
        for (int r = 0; r < 12; ++r) part[tid * 12 + r] = acc[r];
        __syncthreads();
        if (tid < 64) {
            int fb = tid & 15, fj = tid >> 4;
            float si[3] = {0.f, 0.f, 0.f}, sh_[3] = {0.f, 0.f, 0.f};
#pragma unroll
            for (int k2 = 0; k2 < 8; ++k2) {
                const float* pi = part + (k2 * 16 + fb) * 12;
                const float* ph = part + ((128 + k2 * 16 + fb)) * 12;
#pragma unroll
                for (int g = 0; g < 3; ++g) {
                    si[g] += pi[g * 4 + fj];
                    sh_[g] += ph[g * 4 + fj];
                }
            }
            int jg = j0 + fj, bg = b0 + fb;
            float r_ = sigmoidf_(si[0] + bi1[jg] + sh_[0] + bh1[jg]);
            float z_ = sigmoidf_(si[1] + bi1[H + jg] + sh_[1] + bh1[H + jg]);
            float n_ = tanh_fast(si[2] + bi1[2 * H + jg] + r_ * (sh_[2] + bh1[2 * H + jg]));
            f4 hp = ldb16(stH, jg >> 2, fb);
            float hprev = ((const float*)&hp)[jg & 3];
            h1_dst[(size_t)bg * H + jg] = (1.f - z_) * n_ + z_ * hprev;
        }
    }
}

__global__ void copy_hidden_kernel(const float* __restrict__ h0, const float* __restrict__ h1,
                                   float* __restrict__ dst) {
    int i = blockIdx.x * 256 + threadIdx.x;
    dst[i] = h0[i];
    dst[BH + i] = h1[i];
}

extern "C" void kernel_launch(void* const* d_in, const int* in_sizes, int n_in,
                              void* d_out_v, int out_size, void* d_ws, size_t ws_size,
                              hipStream_t stream) {
    const float* enc = (const float*)d_in[0];
    const float* hidden = (const float*)d_in[1];
    const float* target = (const float*)d_in[2];
    const float* Wq = (const float*)d_in[3];
    const float* Wk = (const float*)d_in[4];
    const float* wv = (const float*)d_in[5];
    const float* emb_W = (const float*)d_in[6];
    const float* emb_b = (const float*)d_in[7];
    const float* Wi0 = (const float*)d_in[8];
    const float* Wh0 = (const float*)d_in[9];
    const float* bi0 = (const float*)d_in[10];
    const float* bh0 = (const float*)d_in[11];
    const float* Wi1 = (const float*)d_in[12];
    const float* Wh1 = (const float*)d_in[13];
    const float* bi1 = (const float*)d_in[14];
    const float* bh1 = (const float*)d_in[15];
    const float* last_W = (const float*)d_in[16];
    const float* last_b = (const float*)d_in[17];
    const int* tmask = (const int*)d_in[18];

    float* out = (float*)d_out_v;
    float* out_hidden = out + (size_t)STEPS * B * ODIM;
    float* out_attn = out_hidden + (size_t)2 * BH;

    float* ws = (float*)d_ws;
    float* kpT = ws;                      // 2,097,152
    float* WkT = kpT + 2097152;           // 262,144
    float* gi_emb = WkT + 262144;         // 786,432
    float* gi_ctx = gi_emb + 786432;      // 49,152
    float* h0buf = gi_ctx + 49152;        // 32,768 (2x)
    float* h1buf = h0buf + 32768;         // 32,768 (2x)
    float* qbuf = h1buf + 32768;          // 16,384
    float* ctxbuf = qbuf + 16384;         // 16,384
    float* fbuf = ctxbuf + 16384;         // 8,192
    float* inpbuf = fbuf + 8192;          // 16,384
    float* spart = inpbuf + 16384;        // 32,768
    ushort* Wh0bf = (ushort*)(spart + 32768);     // 786,432 u
    ushort* Wi1bf = Wh0bf + 786432;               // 786,432 u
    ushort* Wh1bf = Wi1bf + 786432;               // 786,432 u
    ushort* Wi0bf = Wh1bf + 786432;               // 1,572,864 u

    // bf16 weight copies
    cvt_bf16_kernel<<<768, 256, 0, stream>>>(Wh0, Wh0bf, 196608);
    cvt_bf16_kernel<<<768, 256, 0, stream>>>(Wi1, Wi1bf, 196608);
    cvt_bf16_kernel<<<768, 256, 0, stream>>>(Wh1, Wh1bf, 196608);
    cvt_bf16_kernel<<<1536, 256, 0, stream>>>(Wi0, Wi0bf, 393216);

    transpose_kernel<<<dim3(16, 16), 256, 0, stream>>>(Wk, WkT, 512, 512, 512);
    kproj_gemm_kernel<<<dim3(64, 8), 256, 0, stream>>>(enc, WkT, kpT);
    init_kernel<<<B, 512, 0, stream>>>(hidden, emb_W, emb_b, h0buf, h1buf, inpbuf);

    int p0 = 0, p1 = 0;
    for (int i = 0; i < STEPS; ++i) {
        int im1 = (i > 0) ? i - 1 : 0;
        const float* h1cur = h1buf + (size_t)p1 * BH;
        attn1_kernel<<<(i > 0) ? 96 : 64, 256, 0, stream>>>(
            64, h1cur, Wq, qbuf, last_W, last_b, target + (size_t)im1 * B * ODIM,
            tmask + im1 * B, fbuf, out + (size_t)im1 * B * ODIM);
        attn2_kernel<<<(i > 0) ? 288 : 256, 256, 0, stream>>>(qbuf, kpT, wv, spart, fbuf,
                                                              emb_W, emb_b, inpbuf);
        attn3_kernel<<<256, 256, 0, stream>>>(spart, enc, ctxbuf, out_attn + (size_t)i * B * T);
        gi_kernel<<<192, 256, 0, stream>>>(ctxbuf, inpbuf, Wi0bf, bi0, gi_ctx,
                                           gi_emb + (size_t)i * B * G3);
        for (int t = 0; t <= i + 1; ++t) {
            int nb0 = (t <= i) ? 256 : 0;
            int nb1 = (t >= 1) ? 256 : 0;
            int tge = (t <= i) ? t : 0;
            cell_kernel<<<nb0 + nb1, 256, 0, stream>>>(
                nb0, h0buf + (size_t)p0 * BH, h0buf + (size_t)(p0 ^ 1) * BH,
                h1buf + (size_t)p1 * BH, h1buf + (size_t)(p1 ^ 1) * BH,
                gi_emb + (size_t)tge * B * G3, gi_ctx, Wh0bf, bh0, Wi1bf, bi1, Wh1bf, bh1);
            if (nb0) p0 ^= 1;
            if (nb1) p1 ^= 1;
        }
    }
    // final lin (step 15)
    attn1_kernel<<<32, 256, 0, stream>>>(0, h1buf + (size_t)p1 * BH, Wq, qbuf, last_W, last_b,
                                         target + (size_t)15 * B * ODIM, tmask + 15 * B, fbuf,
                                         out + (size_t)15 * B * ODIM);
    copy_hidden_kernel<<<64, 256, 0, stream>>>(h0buf + (size_t)p0 * BH, h1buf + (size_t)p1 * BH,
                                               out_hidden);
}